// Round 11
// baseline (651.277 us; speedup 1.0000x reference)
//
#include <hip/hip_runtime.h>
#include <stdint.h>

typedef __attribute__((ext_vector_type(8))) short bf8v;     // 8 bf16 frag (4 VGPR)
typedef __attribute__((ext_vector_type(4))) float f4v;      // MFMA acc / vec ld-st
typedef __attribute__((ext_vector_type(4))) unsigned int u4v;
typedef __attribute__((ext_vector_type(2))) unsigned int u2v;

#define MFMA16(a,b,c) __builtin_amdgcn_mfma_f32_16x16x32_bf16((a),(b),(c),0,0,0)

__device__ __forceinline__ unsigned short f2bf(float f) {
    unsigned u = __float_as_uint(f);
    return (unsigned short)((u + 0x7FFFu + ((u >> 16) & 1u)) >> 16);  // RNE
}
__device__ __forceinline__ float bflo(unsigned w) { return __uint_as_float(w << 16); }
__device__ __forceinline__ float bfhi(unsigned w) { return __uint_as_float(w & 0xFFFF0000u); }
// u16 index into a swizzled bf16 tile, row length L u16s (L>=64):
// XOR bits 3..5 of the k-index with row&7 -> spreads a frag-read over all 32 banks
#define SW(row,k,L) ((row)*(L) + ((k) ^ (((row)&7)<<3)))

// ws layout (bytes)
#define WS_QMK   0u          // bf16 [16384][64] permuted, 2 MiB
#define WS_V     4194304u    // bf16 [16384][64] permuted, 2 MiB
#define WS_AGG   8388608u
#define WS_IDX   12582912u
#define WS_W1T   13631488u   // [256 hid][64 k]  32768 B  (k_att blob start)
#define WS_W2T   13664256u   // [64 ch][256 k]   32768 B
#define WS_WPT   13697024u   // [64 ch][64 k]     8192 B  (blob = 73728 B)
#define WS_WQK   13705216u   // [128 col][256 k] 65536 B
#define WS_WOUT  13770752u   // [256 col][64 k]  32768 B

// ---------------- prep: bf16 transpose + pre-swizzle weight images ----------------
__global__ __launch_bounds__(256) void k_prep(
    const float* __restrict__ w_qkv, const float* __restrict__ w_pos2,
    const float* __restrict__ w_att1, const float* __restrict__ w_att2,
    const float* __restrict__ w_out, char* __restrict__ ws)
{
    int t = blockIdx.x * 256 + threadIdx.x;
    unsigned short* w1i = (unsigned short*)(ws + WS_W1T);
    unsigned short* w2i = (unsigned short*)(ws + WS_W2T);
    unsigned short* wpi = (unsigned short*)(ws + WS_WPT);
    unsigned short* wqi = (unsigned short*)(ws + WS_WQK);
    unsigned short* woi = (unsigned short*)(ws + WS_WOUT);
    if (t < 16384) {                      // W1T[hid][k] = w_att1[k][hid]
        int hid = t >> 6, k = t & 63;
        w1i[hid*64 + (k ^ ((hid&7)<<3))] = f2bf(w_att1[k*256 + hid]);
    } else if (t < 32768) {               // W2T[ch][k] = w_att2[k][ch]
        int i = t - 16384; int ch = i >> 8, k = i & 255;
        w2i[ch*256 + (k ^ ((ch&7)<<3))] = f2bf(w_att2[k*64 + ch]);
    } else if (t < 36864) {               // WPT[ch][k] = w_pos2[k][ch]
        int i = t - 32768; int ch = i >> 6, k = i & 63;
        wpi[ch*64 + (k ^ ((ch&7)<<3))] = f2bf(w_pos2[k*64 + ch]);
    } else if (t < 69632) {               // WqkvT[col][k]: col<64 -> wq-wk, else wv
        int i = t - 36864; int col = i >> 8, k = i & 255;
        float val = (col < 64) ? (w_qkv[k*192 + col] - w_qkv[k*192 + 64 + col])
                               : w_qkv[k*192 + 128 + (col - 64)];
        wqi[col*256 + (k ^ ((col&7)<<3))] = f2bf(val);
    } else if (t < 86016) {               // WoutT[col][k] = w_out[k][col]
        int i = t - 69632; int col = i >> 6, k = i & 63;
        woi[col*64 + (k ^ ((col&7)<<3))] = f2bf(w_out[k*256 + col]);
    }
}

// ---------------- KNN: wave per point, register top-16 ----------------
__global__ __launch_bounds__(256) void k_knn(const float* __restrict__ pos,
                                             int* __restrict__ idxo) {
    const int wid = threadIdx.x >> 6, lane = threadIdx.x & 63;
    const int pid = blockIdx.x * 4 + wid;
    const int b = pid >> 11, i = pid & 2047;
    const float* pb = pos + (size_t)b * 2048 * 3;
    float xi = pb[i*3], yi = pb[i*3+1], zi = pb[i*3+2];
    float d2i = xi*xi; d2i = fmaf(yi, yi, d2i); d2i = fmaf(zi, zi, d2i);
    unsigned long long key[32];
#pragma unroll
    for (int m = 0; m < 32; ++m) {
        int j = m * 64 + lane;
        float xj = pb[j*3], yj = pb[j*3+1], zj = pb[j*3+2];
        float d2j = xj*xj; d2j = fmaf(yj, yj, d2j); d2j = fmaf(zj, zj, d2j);
        float dot = xi*xj; dot = fmaf(yi, yj, dot); dot = fmaf(zi, zj, dot);
        float sim = 2.0f*dot - d2i - d2j;
        unsigned u = __float_as_uint(sim);
        unsigned fk = (u & 0x80000000u) ? ~u : (u | 0x80000000u);
        key[m] = ((unsigned long long)fk << 32) | (unsigned)(0xFFFFFFFFu - (unsigned)j);
    }
    unsigned long long lmax = key[0];
#pragma unroll
    for (int m = 1; m < 32; ++m) lmax = (key[m] > lmax) ? key[m] : lmax;
    int my = 0;
    for (int it = 0; it < 16; ++it) {
        unsigned long long wmax = lmax;
#pragma unroll
        for (int st = 32; st >= 1; st >>= 1) {
            unsigned long long o = __shfl_xor(wmax, st);
            wmax = (o > wmax) ? o : wmax;
        }
        int jw = (int)(0xFFFFFFFFu - (unsigned)(wmax & 0xFFFFFFFFull));
        if (lane == it) my = jw;
        if (lmax == wmax) {               // unique winner lane: remove + recompute
#pragma unroll
            for (int m = 0; m < 32; ++m) if (key[m] == wmax) key[m] = 0ull;
            lmax = key[0];
#pragma unroll
            for (int m = 1; m < 32; ++m) lmax = (key[m] > lmax) ? key[m] : lmax;
        }
    }
    if (lane < 16) idxo[pid * 16 + lane] = b * 2048 + my;
}

// ---------------- qkv: MFMA GEMM [16384x256]@[256x128] -> bf16 permuted qmk | v ----------------
// channel c = mt*16 + q4*4 + j  stored at  p = q4*16 + mt*4 + j  (matches k_att lane layout)
__global__ __launch_bounds__(256, 1) void k_qkv(const float* __restrict__ x,
        const char* __restrict__ wimg, unsigned short* __restrict__ qb,
        unsigned short* __restrict__ vb) {
    extern __shared__ char smem[];
    unsigned short* WQ = (unsigned short*)smem;             // [128][256] swz, 64KB
    unsigned short* XT = (unsigned short*)(smem + 65536);   // [64][256] swz, 32KB
    unsigned short* BQ = (unsigned short*)(smem + 98304);   // [64][64] permuted, 8KB
    unsigned short* BV = (unsigned short*)(smem + 106496);  // [64][64] permuted, 8KB
    const int tid = threadIdx.x, wid = tid >> 6, lane = tid & 63;
    const int q4 = lane >> 4, l15 = lane & 15;
#pragma unroll
    for (int itn = 0; itn < 16; ++itn) {
        int off = itn * 4096 + tid * 16;
        *(u4v*)(smem + off) = *(const u4v*)(wimg + off);
    }
    __syncthreads();
    {   // stage X tile
        int r = tid >> 2, k64 = (tid & 3) * 64;
        const float* xr = x + ((size_t)blockIdx.x * 64 + r) * 256 + k64;
#pragma unroll
        for (int c = 0; c < 8; ++c) {
            f4v a = *(const f4v*)(xr + c*8);
            f4v bq = *(const f4v*)(xr + c*8 + 4);
            bf8v s;
            s[0]=(short)f2bf(a[0]); s[1]=(short)f2bf(a[1]); s[2]=(short)f2bf(a[2]); s[3]=(short)f2bf(a[3]);
            s[4]=(short)f2bf(bq[0]); s[5]=(short)f2bf(bq[1]); s[6]=(short)f2bf(bq[2]); s[7]=(short)f2bf(bq[3]);
            *(bf8v*)&XT[SW(r, k64 + c*8, 256)] = s;
        }
    }
    f4v z = {0.f,0.f,0.f,0.f};
    f4v acc[8];
#pragma unroll
    for (int n = 0; n < 8; ++n) acc[n] = z;
    const int arow = wid*16 + l15;
#pragma unroll
    for (int ks = 0; ks < 8; ++ks) {
        int k0 = ks*32 + q4*8;
        bf8v a = *(const bf8v*)&XT[SW(arow, k0, 256)];
#pragma unroll
        for (int nt = 0; nt < 8; ++nt) {
            bf8v bq = *(const bf8v*)&WQ[SW(nt*16 + l15, k0, 256)];
            acc[nt] = MFMA16(a, bq, acc[nt]);
        }
    }
    // permuted bf16 epilogue via LDS bounce, then coalesced 16B stores
#pragma unroll
    for (int nt = 0; nt < 8; ++nt) {
        int mt = nt & 3;
        unsigned short* B = (nt < 4) ? BQ : BV;
        int pp = (l15 >> 2) * 16 + mt * 4 + (l15 & 3);
#pragma unroll
        for (int j2 = 0; j2 < 4; ++j2) {
            int rl = wid*16 + q4*4 + j2;
            B[rl*64 + pp] = f2bf(acc[nt][j2]);
        }
    }
    __syncthreads();
    size_t base = (size_t)blockIdx.x * 64;
#pragma unroll
    for (int rep = 0; rep < 2; ++rep) {
        int chunk = tid*2 + rep;
        int row = chunk >> 3, c8 = chunk & 7;
        *(u4v*)(qb + (base + row)*64 + c8*8) = *(const u4v*)&BQ[row*64 + c8*8];
        *(u4v*)(vb + (base + row)*64 + c8*8) = *(const u4v*)&BV[row*64 + c8*8];
    }
}

// ---------------- fused attention: 8 waves/block, wave = one point at a time ----------------
// bf16 packed gathers (32B/lane per array), GEMM1 split in halves (no spills),
// weights LDS-resident, one barrier total, softmax/L2norm/agg in-register.
__global__ __launch_bounds__(512, 2) void k_att(
    const unsigned short* __restrict__ qb, const unsigned short* __restrict__ vb,
    const float* __restrict__ pos, const int* __restrict__ idx,
    const float* __restrict__ w_pos1, const float* __restrict__ b_pos1,
    const float* __restrict__ b_pos2, const float* __restrict__ b_att1,
    const float* __restrict__ b_att2, const char* __restrict__ wblob,
    float* __restrict__ agg)
{
    extern __shared__ char smem[];
    unsigned short* W1T = (unsigned short*)smem;            // [256][64] swz
    unsigned short* W2T = (unsigned short*)(smem + 32768);  // [64][256] swz
    unsigned short* WPT = (unsigned short*)(smem + 65536);  // [64][64]  swz
    const int tid = threadIdx.x, wid = tid >> 6, lane = tid & 63;
    const int q4 = lane >> 4, l15 = lane & 15;
    const int r4 = lane >> 2, c16 = (lane & 3) * 16;
    char* wb = smem + 73728 + wid * 10240;                  // per-wave scratch
    unsigned short* P  = (unsigned short*)wb;               // [16][256] bf16 swz
    unsigned short* PH = (unsigned short*)wb;               // [16][64]  (aliases P head)
    unsigned short* H  = (unsigned short*)(wb + 8192);      // [16][64]  bf16 swz

#pragma unroll
    for (int it = 0; it < 9; ++it) {                        // stage 73728B of weights
        int off = it * 8192 + tid * 16;
        *(u4v*)(smem + off) = *(const u4v*)(wblob + off);
    }
    __syncthreads();                                        // only barrier in kernel

#pragma unroll 1
    for (int g = 0; g < 8; ++g) {
        const int p = (blockIdx.x * 8 + wid) * 8 + g;
        const int rowbase = p * 16;

        const int flat_l = idx[rowbase + l15];
        // early packed qk gather: 16 bf16 (this lane's channels) = 32B
        u4v qkp0 = *(const u4v*)(qb + (size_t)flat_l*64 + q4*16);
        u4v qkp1 = *(const u4v*)(qb + (size_t)flat_l*64 + q4*16 + 8);

        // ---- PH = relu(rel @ w_pos1 + b_pos1): lane = (row r4, 16-hid chunk c16) ----
        {
            int flat_r = __shfl(flat_l, r4);
            float cx = pos[p*3], cy = pos[p*3+1], cz = pos[p*3+2];
            float r0 = pos[flat_r*3] - cx, r1 = pos[flat_r*3+1] - cy, r2v = pos[flat_r*3+2] - cz;
            bf8v lo, hi;
#pragma unroll
            for (int u = 0; u < 4; ++u) {
                f4v w0 = *(const f4v*)(w_pos1 + c16 + u*4);
                f4v w1 = *(const f4v*)(w_pos1 + 64 + c16 + u*4);
                f4v w2 = *(const f4v*)(w_pos1 + 128 + c16 + u*4);
                f4v bb = *(const f4v*)(b_pos1 + c16 + u*4);
#pragma unroll
                for (int j = 0; j < 4; ++j) {
                    float t = fmaf(r2v, w2[j], fmaf(r1, w1[j], fmaf(r0, w0[j], bb[j])));
                    t = fmaxf(t, 0.f);
                    if (u < 2) lo[u*4+j] = (short)f2bf(t);
                    else       hi[(u-2)*4+j] = (short)f2bf(t);
                }
            }
            *(bf8v*)&PH[SW(r4, c16, 64)] = lo;
            *(bf8v*)&PH[SW(r4, c16+8, 64)] = hi;
        }

        // ---- GEMM0: rpe[ch][row] = WPT @ PH^T, acc init = b_pos2 ----
        f4v rp[4];
#pragma unroll
        for (int mt = 0; mt < 4; ++mt) rp[mt] = *(const f4v*)(b_pos2 + mt*16 + q4*4);
#pragma unroll
        for (int ks = 0; ks < 2; ++ks) {
            int k0 = ks*32 + q4*8;
            bf8v bfr = *(const bf8v*)&PH[SW(l15, k0, 64)];
#pragma unroll
            for (int mt = 0; mt < 4; ++mt)
                rp[mt] = MFMA16(*(const bf8v*)&WPT[SW(mt*16+l15, k0, 64)], bfr, rp[mt]);
        }

        // ---- h = rpe + qk(bf16 unpack) -> H (bf16); rp stays live for agg ----
#define QW(w) ((w) < 4 ? qkp0[(w)] : qkp1[(w)-4])
#pragma unroll
        for (int mt = 0; mt < 4; ++mt) {
            float h0 = rp[mt][0] + bflo(QW(mt*2));
            float h1 = rp[mt][1] + bfhi(QW(mt*2));
            float h2 = rp[mt][2] + bflo(QW(mt*2+1));
            float h3 = rp[mt][3] + bfhi(QW(mt*2+1));
            u2v pp;
            pp[0] = (unsigned)f2bf(h0) | ((unsigned)f2bf(h1) << 16);
            pp[1] = (unsigned)f2bf(h2) | ((unsigned)f2bf(h3) << 16);
            *(u2v*)&H[SW(l15, mt*16 + q4*4, 64)] = pp;
        }
#undef QW
        // issue vv gather now; consumed only after GEMM1+GEMM2 (latency hidden)
        u4v vvp0 = *(const u4v*)(vb + (size_t)flat_l*64 + q4*16);
        u4v vvp1 = *(const u4v*)(vb + (size_t)flat_l*64 + q4*16 + 8);

        // ---- GEMM1 in two halves (c1 half = 32 VGPRs, no spill): relu -> P ----
#pragma unroll
        for (int hf = 0; hf < 2; ++hf) {
            f4v c1h[8];
#pragma unroll
            for (int m = 0; m < 8; ++m)
                c1h[m] = *(const f4v*)(b_att1 + (hf*8 + m)*16 + q4*4);
#pragma unroll
            for (int ks = 0; ks < 2; ++ks) {
                int k0 = ks*32 + q4*8;
                bf8v bfr = *(const bf8v*)&H[SW(l15, k0, 64)];
#pragma unroll
                for (int m = 0; m < 8; ++m)
                    c1h[m] = MFMA16(*(const bf8v*)&W1T[SW((hf*8+m)*16+l15, k0, 64)], bfr, c1h[m]);
            }
#pragma unroll
            for (int m = 0; m < 8; ++m) {
                int mtg = hf*8 + m;
                float t0 = fmaxf(c1h[m][0], 0.f), t1 = fmaxf(c1h[m][1], 0.f);
                float t2 = fmaxf(c1h[m][2], 0.f), t3 = fmaxf(c1h[m][3], 0.f);
                u2v pp;
                pp[0] = (unsigned)f2bf(t0) | ((unsigned)f2bf(t1) << 16);
                pp[1] = (unsigned)f2bf(t2) | ((unsigned)f2bf(t3) << 16);
                *(u2v*)&P[SW(l15, mtg*16 + q4*4, 256)] = pp;
            }
        }

        // ---- GEMM2: sim[ch][row] = W2T @ P^T, acc init = b_att2 ----
        f4v ss[4];
#pragma unroll
        for (int mt = 0; mt < 4; ++mt) ss[mt] = *(const f4v*)(b_att2 + mt*16 + q4*4);
#pragma unroll
        for (int ks = 0; ks < 8; ++ks) {
            int k0 = ks*32 + q4*8;
            bf8v bfr = *(const bf8v*)&P[SW(l15, k0, 256)];
#pragma unroll
            for (int mt = 0; mt < 4; ++mt)
                ss[mt] = MFMA16(*(const bf8v*)&W2T[SW(mt*16+l15, k0, 256)], bfr, ss[mt]);
        }

        // ---- softmax over 64 ch (in-lane 16 + xor16/32), L2norm+agg over rows (xor1..8) ----
        float e[16]; float mx = -3.4e38f;
#pragma unroll
        for (int i = 0; i < 16; ++i) { e[i] = ss[i>>2][i&3]; mx = fmaxf(mx, e[i]); }
        mx = fmaxf(mx, __shfl_xor(mx, 16));
        mx = fmaxf(mx, __shfl_xor(mx, 32));
        float sum = 0.f;
#pragma unroll
        for (int i = 0; i < 16; ++i) { e[i] = __expf(e[i] - mx); sum += e[i]; }
        sum += __shfl_xor(sum, 16);
        sum += __shfl_xor(sum, 32);
        float inv = 1.0f / sum;
        float nn[16], av[16];
#define VW(w) ((w) < 4 ? vvp0[(w)] : vvp1[(w)-4])
#pragma unroll
        for (int i = 0; i < 16; ++i) {
            int mt = i >> 2, j = i & 3;
            float vf = (j & 1) ? bfhi(VW(mt*2 + (j>>1))) : bflo(VW(mt*2 + (j>>1)));
            e[i] *= inv;
            nn[i] = e[i] * e[i];
            av[i] = e[i] * (rp[mt][j] + vf);
        }
#undef VW
#pragma unroll
        for (int st = 1; st <= 8; st <<= 1) {
#pragma unroll
            for (int i = 0; i < 16; ++i) {
                nn[i] += __shfl_xor(nn[i], st);
                av[i] += __shfl_xor(av[i], st);
            }
        }
        if (l15 == 0) {
#pragma unroll
            for (int mt = 0; mt < 4; ++mt) {
                f4v o;
#pragma unroll
                for (int j = 0; j < 4; ++j)
                    o[j] = av[mt*4+j] / fmaxf(sqrtf(nn[mt*4+j]), 1e-12f);
                *(f4v*)(agg + (size_t)p*64 + mt*16 + q4*4) = o;
            }
        }
    }
}

// ---------------- out: MFMA GEMM [16384 x 64] @ [64 x 256] + b_out ----------------
__global__ __launch_bounds__(256, 1) void k_out(const float* __restrict__ agg,
        const char* __restrict__ wimg, const float* __restrict__ b_out,
        float* __restrict__ outp) {
    extern __shared__ char smem[];
    unsigned short* WO = (unsigned short*)smem;            // [256][64] swz
    unsigned short* AT = (unsigned short*)(smem + 32768);  // [64][64]  swz
    const int tid = threadIdx.x, wid = tid >> 6, lane = tid & 63;
    const int q4 = lane >> 4, l15 = lane & 15;
#pragma unroll
    for (int itn = 0; itn < 8; ++itn) {
        int off = itn * 4096 + tid * 16;
        *(u4v*)(smem + off) = *(const u4v*)(wimg + off);
    }
    __syncthreads();
    {
        int r = tid >> 2, k16 = (tid & 3) * 16;
        const float* ar = agg + ((size_t)blockIdx.x * 64 + r) * 64 + k16;
        bf8v lo, hi;
#pragma unroll
        for (int i = 0; i < 16; ++i) {
            float t = ar[i];
            if (i < 8) lo[i] = (short)f2bf(t); else hi[i-8] = (short)f2bf(t);
        }
        *(bf8v*)&AT[SW(r, k16, 64)] = lo;
        *(bf8v*)&AT[SW(r, k16+8, 64)] = hi;
    }
    f4v z = {0.f,0.f,0.f,0.f};
    f4v acc[16];
#pragma unroll
    for (int nt = 0; nt < 16; ++nt) acc[nt] = z;
#pragma unroll
    for (int ks = 0; ks < 2; ++ks) {
        int k0 = ks*32 + q4*8;
        bf8v a = *(const bf8v*)&AT[SW(wid*16 + l15, k0, 64)];
#pragma unroll
        for (int nt = 0; nt < 16; ++nt) {
            bf8v bq = *(const bf8v*)&WO[SW(nt*16 + l15, k0, 64)];
            acc[nt] = MFMA16(a, bq, acc[nt]);
        }
    }
    size_t rbase = (size_t)blockIdx.x * 64 + wid*16 + q4*4;
#pragma unroll
    for (int nt = 0; nt < 16; ++nt) {
        int col = nt*16 + l15;
        float bo = b_out[col];
#pragma unroll
        for (int j = 0; j < 4; ++j)
            outp[(rbase + j)*256 + col] = acc[nt][j] + bo;
    }
}

extern "C" void kernel_launch(void* const* d_in, const int* in_sizes, int n_in,
                              void* d_out, int out_size, void* d_ws, size_t ws_size,
                              hipStream_t stream) {
    (void)in_sizes; (void)n_in; (void)out_size; (void)ws_size;
    const float* x      = (const float*)d_in[0];
    const float* pos    = (const float*)d_in[1];
    const float* w_qkv  = (const float*)d_in[2];
    const float* w_pos1 = (const float*)d_in[3];
    const float* b_pos1 = (const float*)d_in[4];
    const float* w_pos2 = (const float*)d_in[5];
    const float* b_pos2 = (const float*)d_in[6];
    const float* w_att1 = (const float*)d_in[7];
    const float* b_att1 = (const float*)d_in[8];
    const float* w_att2 = (const float*)d_in[9];
    const float* b_att2 = (const float*)d_in[10];
    const float* w_out  = (const float*)d_in[11];
    const float* b_out  = (const float*)d_in[12];
    float* outp = (float*)d_out;

    char* ws = (char*)d_ws;
    unsigned short* qb = (unsigned short*)(ws + WS_QMK);
    unsigned short* vb = (unsigned short*)(ws + WS_V);
    float* agg = (float*)(ws + WS_AGG);
    int*   idx = (int*)(ws + WS_IDX);

    k_prep<<<dim3(336), dim3(256), 0, stream>>>(w_qkv, w_pos2, w_att1, w_att2, w_out, ws);
    k_knn<<<dim3(4096), dim3(256), 0, stream>>>(pos, idx);
    k_qkv<<<dim3(256), dim3(256), 114688, stream>>>(x, ws + WS_WQK, qb, vb);
    k_att<<<dim3(256), dim3(512), 155648, stream>>>(qb, vb, pos, idx,
                                                    w_pos1, b_pos1, b_pos2, b_att1, b_att2,
                                                    ws + WS_W1T, agg);
    k_out<<<dim3(256), dim3(256), 40960, stream>>>(agg, ws + WS_WOUT, b_out, outp);
}